// Round 8
// baseline (911.174 us; speedup 1.0000x reference)
//
#include <hip/hip_runtime.h>

constexpr int Bm = 8, Hm = 16, Sm = 1024, Dm = 64;
constexpr int BH = Bm * Hm;          // 128
constexpr int NBLK = BH * (Sm / 16); // 8192 blocks

typedef short short8  __attribute__((ext_vector_type(8)));
typedef float floatx4 __attribute__((ext_vector_type(4)));
typedef float floatx2 __attribute__((ext_vector_type(2)));
typedef int   intx4   __attribute__((ext_vector_type(4)));

__device__ inline unsigned short f2bf(float f) {
    unsigned u = __builtin_bit_cast(unsigned, f);
    u += 0x7fffu + ((u >> 16) & 1u);          // RNE
    return (unsigned short)(u >> 16);
}
__device__ inline float bf2f(unsigned short h) {
    unsigned u = ((unsigned)h) << 16;
    return __builtin_bit_cast(float, u);
}

// ---------------------------------------------------------------------------
// Pre-pass: K fp32 -> bf16 (same layout), V fp32 -> bf16 V^T ([bh][d][key]).
// ---------------------------------------------------------------------------
__global__ __launch_bounds__(256)
void preconv(const float* __restrict__ K, const float* __restrict__ V,
             unsigned short* __restrict__ Kbf, unsigned short* __restrict__ VT)
{
    __shared__ unsigned short tile[64][72];

    const int blk = blockIdx.x;               // 128 bh * 16 key-tiles
    const int bh  = blk >> 4;
    const int t   = blk & 15;
    const int tid = threadIdx.x;
    const int row = tid >> 2;
    const int c0  = (tid & 3) << 4;

    {
        const float* src = K + ((size_t)bh * Sm + t * 64 + row) * Dm + c0;
        unsigned short* dst = Kbf + ((size_t)bh * Sm + t * 64 + row) * Dm + c0;
        floatx4 a0 = *(const floatx4*)(src);
        floatx4 a1 = *(const floatx4*)(src + 4);
        floatx4 a2 = *(const floatx4*)(src + 8);
        floatx4 a3 = *(const floatx4*)(src + 12);
        short8 p0, p1;
        #pragma unroll
        for (int i = 0; i < 4; ++i) {
            p0[i]     = (short)f2bf(a0[i]);
            p0[i + 4] = (short)f2bf(a1[i]);
            p1[i]     = (short)f2bf(a2[i]);
            p1[i + 4] = (short)f2bf(a3[i]);
        }
        *(short8*)(dst)     = p0;
        *(short8*)(dst + 8) = p1;
    }
    {
        const float* src = V + ((size_t)bh * Sm + t * 64 + row) * Dm + c0;
        floatx4 a0 = *(const floatx4*)(src);
        floatx4 a1 = *(const floatx4*)(src + 4);
        floatx4 a2 = *(const floatx4*)(src + 8);
        floatx4 a3 = *(const floatx4*)(src + 12);
        short8 p0, p1;
        #pragma unroll
        for (int i = 0; i < 4; ++i) {
            p0[i]     = (short)f2bf(a0[i]);
            p0[i + 4] = (short)f2bf(a1[i]);
            p1[i]     = (short)f2bf(a2[i]);
            p1[i + 4] = (short)f2bf(a3[i]);
        }
        *(short8*)(&tile[row][c0])     = p0;
        *(short8*)(&tile[row][c0 + 8]) = p1;
    }
    __syncthreads();
    {
        const int drow = tid >> 2;
        const int kc0  = (tid & 3) << 4;
        unsigned short* dst = VT + ((size_t)bh * Dm + drow) * Sm + t * 64 + kc0;
        short8 p0, p1;
        #pragma unroll
        for (int j = 0; j < 8; ++j) {
            p0[j] = (short)tile[kc0 + j][drow];
            p1[j] = (short)tile[kc0 + 8 + j][drow];
        }
        *(short8*)(dst)     = p0;
        *(short8*)(dst + 8) = p1;
    }
}

// ---------------------------------------------------------------------------
// Main fused kernel -- 512-thread blocks (8 waves).
// R7 post-mortem: 256-thread blocks were stuck at 4 blocks x 4 waves = 16
// waves/CU (45%); dur invariant across 3 structural changes => latency-bound,
// TLP-starved. 512 threads x 32 KB LDS -> 4 blocks/CU = 32 waves/CU (100%
// target) under BOTH the 128KB- and 160KB-usable-LDS hypotheses.
// Per block: 16 q-rows x 1024 keys. Wave w: phase A covers k-tiles
// [8w, 8w+8), phase B keys [128w, 128w+128). Softmax: 32 threads/row.
// Strip: 16 x 1024 bf16, XOR-swizzled (col ^ ((row&7)<<3)); row max fused
// into phase A registers, exchanged via global scratch Gmx (8 segs/row).
// ---------------------------------------------------------------------------
__global__ __launch_bounds__(512, 8)
void attn_fused(const float* __restrict__ Q, const unsigned short* __restrict__ Kbf,
                const unsigned short* __restrict__ VT, const int* __restrict__ Msk,
                float* __restrict__ Gmx,
                float* __restrict__ Out, float* __restrict__ Attn)
{
    __shared__ __align__(16) unsigned short strip[16 * 1024];   // 32 KB exact

    const int tid  = threadIdx.x;
    const int wave = tid >> 6;        // 0..7
    const int lane = tid & 63;
    const int quad = lane >> 4;
    const int ln   = lane & 15;

    const int bid = (blockIdx.x & 7) * (NBLK >> 3) + (blockIdx.x >> 3);  // XCD swizzle
    const int bh = bid >> 6;
    const int qt = bid & 63;
    const int q0 = qt << 4;
    const int b  = bh >> 4;           // H = 16

    const float* Qb = Q + (size_t)bh * (Sm * Dm);
    const unsigned short* Kb = Kbf + (size_t)bh * (Sm * Dm);
    const unsigned short* Vb = VT + (size_t)bh * (Dm * Sm);

    // ---- Q fragments, 1/sqrt(64)=0.125 folded in (exact: power of 2) ----
    short8 aq0, aq1;
    {
        const float* qrow = Qb + (q0 + ln) * Dm + quad * 8;
        floatx4 a = *(const floatx4*)(qrow);
        floatx4 c = *(const floatx4*)(qrow + 4);
        floatx4 d = *(const floatx4*)(qrow + 32);
        floatx4 e = *(const floatx4*)(qrow + 36);
        #pragma unroll
        for (int i = 0; i < 4; ++i) {
            aq0[i]     = (short)f2bf(a[i] * 0.125f);
            aq0[i + 4] = (short)f2bf(c[i] * 0.125f);
            aq1[i]     = (short)f2bf(d[i] * 0.125f);
            aq1[i + 4] = (short)f2bf(e[i] * 0.125f);
        }
    }

    // ---- Phase A: scores -> swizzled strip; fused per-row max in registers.
    float rm[4] = {-1e30f, -1e30f, -1e30f, -1e30f};
    for (int kt = wave * 8; kt < wave * 8 + 8; ++kt) {
        const unsigned short* krow = Kb + (kt * 16 + ln) * Dm + quad * 8;
        short8 b0 = *(const short8*)(krow);
        short8 b1 = *(const short8*)(krow + 32);
        floatx4 c = {0.f, 0.f, 0.f, 0.f};
        c = __builtin_amdgcn_mfma_f32_16x16x32_bf16(aq0, b0, c, 0, 0, 0);
        c = __builtin_amdgcn_mfma_f32_16x16x32_bf16(aq1, b1, c, 0, 0, 0);
        const int colb = kt * 16 + ln;
        #pragma unroll
        for (int r = 0; r < 4; ++r) {
            const int row = quad * 4 + r;
            rm[r] = fmaxf(rm[r], c[r]);
            strip[row * 1024 + (colb ^ ((row & 7) << 3))] = f2bf(c[r]);
        }
    }
    #pragma unroll
    for (int off = 8; off >= 1; off >>= 1)
        #pragma unroll
        for (int r = 0; r < 4; ++r)
            rm[r] = fmaxf(rm[r], __shfl_xor(rm[r], off, 16));
    if (ln == 0) {                               // one lane per quad publishes
        float* g = Gmx + ((size_t)bid << 7) + wave * 16 + quad * 4;
        g[0] = rm[0]; g[1] = rm[1]; g[2] = rm[2]; g[3] = rm[3];
    }
    __syncthreads();                             // orders LDS + block-scope global

    // ---- Softmax (2 passes): 32 threads per row, 32 elems each ----
    {
        const int row = tid >> 5, l = tid & 31;
        const int sw  = (row & 7) << 3;
        unsigned short* srow = strip + row * 1024;

        const float* g = Gmx + ((size_t)bid << 7) + row;
        float mx = g[0];
        #pragma unroll
        for (int s = 1; s < 8; ++s) mx = fmaxf(mx, g[s * 16]);
        mx = bf2f(f2bf(mx));   // == max over bf16-rounded scores (RNE monotone)

        float sum = 0.f;
        #pragma unroll
        for (int i = 0; i < 4; ++i) {
            unsigned short* p8 = srow + ((l * 8 + i * 256) ^ sw);
            short8 v = *(const short8*)p8;
            short8 e;
            #pragma unroll
            for (int j = 0; j < 8; ++j) {
                float x = __expf(bf2f((unsigned short)v[j]) - mx);
                sum += x;
                e[j] = (short)f2bf(x);
            }
            *(short8*)p8 = e;
        }
        #pragma unroll
        for (int off = 16; off >= 1; off >>= 1) sum += __shfl_xor(sum, off, 32);
        const float rn = 1.f / sum;

        const int* mrow  = Msk + (size_t)b * (Sm * Sm) + (size_t)(q0 + row) * Sm;
        float*     arow  = Attn + ((size_t)bh * Sm + (q0 + row)) * Sm;
        #pragma unroll
        for (int i = 0; i < 4; ++i) {
            const int c0 = l * 8 + i * 256;           // logical column
            unsigned short* p8 = srow + (c0 ^ sw);    // swizzled strip location
            short8 v  = *(const short8*)p8;
            intx4  m0 = *(const intx4*)(mrow + c0);
            intx4  m1 = *(const intx4*)(mrow + c0 + 4);
            float p[8];
            #pragma unroll
            for (int j = 0; j < 4; ++j) {
                p[j]     = (m0[j] != 0) ? bf2f((unsigned short)v[j])     * rn : -100000.f;
                p[j + 4] = (m1[j] != 0) ? bf2f((unsigned short)v[j + 4]) * rn : -100000.f;
            }
            floatx4 o0, o1;
            short8 pf;
            #pragma unroll
            for (int j = 0; j < 4; ++j) { o0[j] = p[j]; o1[j] = p[j + 4]; }
            #pragma unroll
            for (int j = 0; j < 8; ++j) pf[j] = (short)f2bf(p[j]);
            *(short8*)p8 = pf;                        // strip now holds P' (bf16)
            *(floatx4*)(arow + c0)     = o0;
            *(floatx4*)(arow + c0 + 4) = o1;
        }
    }
    __syncthreads();

    // ---- Phase B: O = P' @ V. Wave w covers keys [128w, 128w+128). ----
    floatx4 acc[4] = {{0,0,0,0},{0,0,0,0},{0,0,0,0},{0,0,0,0}};
    for (int kb = wave * 128; kb < wave * 128 + 128; kb += 32) {
        short8 af = *(const short8*)(strip + ln * 1024 + ((kb + quad * 8) ^ ((ln & 7) << 3)));
        const unsigned short* vbase = Vb + kb + quad * 8;
        #pragma unroll
        for (int n0 = 0; n0 < 4; ++n0) {
            short8 bf = *(const short8*)(vbase + (size_t)(n0 * 16 + ln) * Sm);
            acc[n0] = __builtin_amdgcn_mfma_f32_16x16x32_bf16(af, bf, acc[n0], 0, 0, 0);
        }
    }
    __syncthreads();

    // ---- Cross-wave partial reduce for O (strip reused as [8][16][64] fp32) ----
    float* part = (float*)strip;                 // 8192 floats = 32 KB exact
    #pragma unroll
    for (int n0 = 0; n0 < 4; ++n0)
        #pragma unroll
        for (int r = 0; r < 4; ++r)
            part[wave * 1024 + (quad * 4 + r) * 64 + n0 * 16 + ln] = acc[n0][r];
    __syncthreads();
    {
        const int o2 = tid * 2;                  // 1024 outputs, 2 per thread
        floatx2 s = *(const floatx2*)(part + o2);
        #pragma unroll
        for (int w = 1; w < 8; ++w) s += *(const floatx2*)(part + w * 1024 + o2);
        const int row = o2 >> 6, dc = o2 & 63;
        *(floatx2*)(Out + (size_t)bh * (Sm * Dm) + (size_t)(q0 + row) * Dm + dc) = s;
    }
}

// ---------------------------------------------------------------------------
// Legacy fallback (fp32 K/V direct, round-1-verified) -- only if ws too small.
// ---------------------------------------------------------------------------
__global__ __launch_bounds__(256, 4)
void attn_fused_f32(const float* __restrict__ Q, const float* __restrict__ K,
                    const float* __restrict__ V, const int* __restrict__ Msk,
                    float* __restrict__ Out, float* __restrict__ Attn)
{
    constexpr int STRIDE = 1040;
    __shared__ __align__(16) unsigned short strip[16 * STRIDE];

    const int tid  = threadIdx.x;
    const int wave = tid >> 6;
    const int lane = tid & 63;
    const int quad = lane >> 4;
    const int ln   = lane & 15;

    const int bid = (blockIdx.x & 7) * (NBLK >> 3) + (blockIdx.x >> 3);
    const int bh = bid >> 6;
    const int qt = bid & 63;
    const int q0 = qt << 4;
    const int b  = bh >> 4;

    const float* Qb = Q + (size_t)bh * (Sm * Dm);
    const float* Kb = K + (size_t)bh * (Sm * Dm);
    const float* Vb = V + (size_t)bh * (Sm * Dm);

    short8 aq0, aq1;
    {
        const float* qrow = Qb + (q0 + ln) * Dm + quad * 8;
        floatx4 a = *(const floatx4*)(qrow);
        floatx4 c = *(const floatx4*)(qrow + 4);
        floatx4 d = *(const floatx4*)(qrow + 32);
        floatx4 e = *(const floatx4*)(qrow + 36);
        #pragma unroll
        for (int i = 0; i < 4; ++i) {
            aq0[i]     = (short)f2bf(a[i] * 0.125f);
            aq0[i + 4] = (short)f2bf(c[i] * 0.125f);
            aq1[i]     = (short)f2bf(d[i] * 0.125f);
            aq1[i + 4] = (short)f2bf(e[i] * 0.125f);
        }
    }

    for (int kt = wave * 16; kt < wave * 16 + 16; ++kt) {
        const float* krow = Kb + (kt * 16 + ln) * Dm + quad * 8;
        floatx4 k0 = *(const floatx4*)(krow);
        floatx4 k1 = *(const floatx4*)(krow + 4);
        floatx4 k2 = *(const floatx4*)(krow + 32);
        floatx4 k3 = *(const floatx4*)(krow + 36);
        short8 b0, b1;
        #pragma unroll
        for (int i = 0; i < 4; ++i) {
            b0[i]     = (short)f2bf(k0[i]);
            b0[i + 4] = (short)f2bf(k1[i]);
            b1[i]     = (short)f2bf(k2[i]);
            b1[i + 4] = (short)f2bf(k3[i]);
        }
        floatx4 c = {0.f, 0.f, 0.f, 0.f};
        c = __builtin_amdgcn_mfma_f32_16x16x32_bf16(aq0, b0, c, 0, 0, 0);
        c = __builtin_amdgcn_mfma_f32_16x16x32_bf16(aq1, b1, c, 0, 0, 0);
        const int colb = kt * 16 + ln;
        #pragma unroll
        for (int r = 0; r < 4; ++r)
            strip[(quad * 4 + r) * STRIDE + colb] = f2bf(c[r]);
    }
    __syncthreads();

    {
        const int row = tid >> 4, l = tid & 15;
        unsigned short* srow = strip + row * STRIDE;

        float mx = -1e30f;
        #pragma unroll
        for (int i = 0; i < 8; ++i) {
            short8 v = *(const short8*)(srow + l * 8 + i * 128);
            #pragma unroll
            for (int j = 0; j < 8; ++j) mx = fmaxf(mx, bf2f((unsigned short)v[j]));
        }
        #pragma unroll
        for (int off = 8; off >= 1; off >>= 1) mx = fmaxf(mx, __shfl_xor(mx, off, 16));

        float sum = 0.f;
        #pragma unroll
        for (int i = 0; i < 8; ++i) {
            short8 v = *(const short8*)(srow + l * 8 + i * 128);
            short8 e;
            #pragma unroll
            for (int j = 0; j < 8; ++j) {
                float x = __expf(bf2f((unsigned short)v[j]) - mx);
                sum += x;
                e[j] = (short)f2bf(x);
            }
            *(short8*)(srow + l * 8 + i * 128) = e;
        }
        #pragma unroll
        for (int off = 8; off >= 1; off >>= 1) sum += __shfl_xor(sum, off, 16);
        const float rn = 1.f / sum;

        const int* mrow  = Msk + (size_t)b * (Sm * Sm) + (size_t)(q0 + row) * Sm;
        float*     arow  = Attn + ((size_t)bh * Sm + (q0 + row)) * Sm;
        #pragma unroll
        for (int i = 0; i < 8; ++i) {
            const int c0 = l * 8 + i * 128;
            short8 v  = *(const short8*)(srow + c0);
            intx4  m0 = *(const intx4*)(mrow + c0);
            intx4  m1 = *(const intx4*)(mrow + c0 + 4);
            float p[8];
            #pragma unroll
            for (int j = 0; j < 4; ++j) {
                p[j]     = (m0[j] != 0) ? bf2f((unsigned short)v[j])     * rn : -100000.f;
                p[j + 4] = (m1[j] != 0) ? bf2f((unsigned short)v[j + 4]) * rn : -100000.f;
            }
            floatx4 o0, o1;
            short8 pf;
            #pragma unroll
            for (int j = 0; j < 4; ++j) { o0[j] = p[j]; o1[j] = p[j + 4]; }
            #pragma unroll
            for (int j = 0; j < 8; ++j) pf[j] = (short)f2bf(p[j]);
            *(short8*)(srow + c0) = pf;
            *(floatx4*)(arow + c0)     = o0;
            *(floatx4*)(arow + c0 + 4) = o1;
        }
    }
    __syncthreads();

    floatx4 acc[4] = {{0,0,0,0},{0,0,0,0},{0,0,0,0},{0,0,0,0}};
    for (int kb = wave * 256; kb < wave * 256 + 256; kb += 32) {
        short8 af = *(const short8*)(strip + ln * STRIDE + kb + quad * 8);
        const float* vbase = Vb + (kb + quad * 8) * Dm + ln;
        #pragma unroll
        for (int n0 = 0; n0 < 4; ++n0) {
            short8 bf;
            #pragma unroll
            for (int j = 0; j < 8; ++j)
                bf[j] = (short)f2bf(vbase[j * Dm + n0 * 16]);
            acc[n0] = __builtin_amdgcn_mfma_f32_16x16x32_bf16(af, bf, acc[n0], 0, 0, 0);
        }
    }
    __syncthreads();

    float* part = (float*)strip;
    #pragma unroll
    for (int n0 = 0; n0 < 4; ++n0)
        #pragma unroll
        for (int r = 0; r < 4; ++r)
            part[wave * 1024 + (quad * 4 + r) * 64 + n0 * 16 + ln] = acc[n0][r];
    __syncthreads();
    {
        const int o4 = tid * 4;
        floatx4 s = *(const floatx4*)(part + o4);
        s += *(const floatx4*)(part + 1024 + o4);
        s += *(const floatx4*)(part + 2048 + o4);
        s += *(const floatx4*)(part + 3072 + o4);
        const int row = o4 >> 6, dc = o4 & 63;
        *(floatx4*)(Out + (size_t)bh * (Sm * Dm) + (size_t)(q0 + row) * Dm + dc) = s;
    }
}

extern "C" void kernel_launch(void* const* d_in, const int* in_sizes, int n_in,
                              void* d_out, int out_size, void* d_ws, size_t ws_size,
                              hipStream_t stream)
{
    const float* Q   = (const float*)d_in[0];
    const float* K   = (const float*)d_in[1];
    const float* V   = (const float*)d_in[2];
    const int*   Msk = (const int*)d_in[3];
    float* Out  = (float*)d_out;
    float* Attn = Out + (size_t)Bm * Hm * Sm * Dm;   // out first, then attn (return order)

    const size_t nElem = (size_t)BH * Sm * Dm;                  // 8.39M
    const size_t bfBytes = nElem * 2 * sizeof(unsigned short);  // Kbf + VT = 32 MB
    const size_t gmxBytes = (size_t)NBLK * 128 * sizeof(float); // 4 MB
    const size_t need = bfBytes + gmxBytes;

    if (d_ws != nullptr && ws_size >= need) {
        unsigned short* Kbf = (unsigned short*)d_ws;
        unsigned short* VT  = Kbf + nElem;
        float*          Gmx = (float*)(VT + nElem);
        preconv<<<dim3(BH * 16), dim3(256), 0, stream>>>(K, V, Kbf, VT);
        attn_fused<<<dim3(NBLK), dim3(512), 0, stream>>>(Q, Kbf, VT, Msk, Gmx, Out, Attn);
    } else {
        attn_fused_f32<<<dim3(NBLK), dim3(256), 0, stream>>>(Q, K, V, Msk, Out, Attn);
    }
}

// Round 9
// 866.735 us; speedup vs baseline: 1.0513x; 1.0513x over previous
//
#include <hip/hip_runtime.h>

constexpr int Bm = 8, Hm = 16, Sm = 1024, Dm = 64;
constexpr int BH = Bm * Hm;          // 128
constexpr int NBLK = BH * (Sm / 16); // 8192 blocks

typedef short short8  __attribute__((ext_vector_type(8)));
typedef float floatx4 __attribute__((ext_vector_type(4)));
typedef int   intx4   __attribute__((ext_vector_type(4)));

__device__ inline unsigned short f2bf(float f) {
    unsigned u = __builtin_bit_cast(unsigned, f);
    u += 0x7fffu + ((u >> 16) & 1u);          // RNE
    return (unsigned short)(u >> 16);
}
__device__ inline float bf2f(unsigned short h) {
    unsigned u = ((unsigned)h) << 16;
    return __builtin_bit_cast(float, u);
}

// ---------------------------------------------------------------------------
// Pre-pass 1: K fp32 -> bf16 (same layout), V fp32 -> bf16 V^T ([bh][d][key]).
// ---------------------------------------------------------------------------
__global__ __launch_bounds__(256)
void preconv(const float* __restrict__ K, const float* __restrict__ V,
             unsigned short* __restrict__ Kbf, unsigned short* __restrict__ VT)
{
    __shared__ unsigned short tile[64][72];

    const int blk = blockIdx.x;               // 128 bh * 16 key-tiles
    const int bh  = blk >> 4;
    const int t   = blk & 15;
    const int tid = threadIdx.x;
    const int row = tid >> 2;
    const int c0  = (tid & 3) << 4;

    {
        const float* src = K + ((size_t)bh * Sm + t * 64 + row) * Dm + c0;
        unsigned short* dst = Kbf + ((size_t)bh * Sm + t * 64 + row) * Dm + c0;
        floatx4 a0 = *(const floatx4*)(src);
        floatx4 a1 = *(const floatx4*)(src + 4);
        floatx4 a2 = *(const floatx4*)(src + 8);
        floatx4 a3 = *(const floatx4*)(src + 12);
        short8 p0, p1;
        #pragma unroll
        for (int i = 0; i < 4; ++i) {
            p0[i]     = (short)f2bf(a0[i]);
            p0[i + 4] = (short)f2bf(a1[i]);
            p1[i]     = (short)f2bf(a2[i]);
            p1[i + 4] = (short)f2bf(a3[i]);
        }
        *(short8*)(dst)     = p0;
        *(short8*)(dst + 8) = p1;
    }
    {
        const float* src = V + ((size_t)bh * Sm + t * 64 + row) * Dm + c0;
        floatx4 a0 = *(const floatx4*)(src);
        floatx4 a1 = *(const floatx4*)(src + 4);
        floatx4 a2 = *(const floatx4*)(src + 8);
        floatx4 a3 = *(const floatx4*)(src + 12);
        short8 p0, p1;
        #pragma unroll
        for (int i = 0; i < 4; ++i) {
            p0[i]     = (short)f2bf(a0[i]);
            p0[i + 4] = (short)f2bf(a1[i]);
            p1[i]     = (short)f2bf(a2[i]);
            p1[i + 4] = (short)f2bf(a3[i]);
        }
        *(short8*)(&tile[row][c0])     = p0;
        *(short8*)(&tile[row][c0 + 8]) = p1;
    }
    __syncthreads();
    {
        const int drow = tid >> 2;
        const int kc0  = (tid & 3) << 4;
        unsigned short* dst = VT + ((size_t)bh * Dm + drow) * Sm + t * 64 + kc0;
        short8 p0, p1;
        #pragma unroll
        for (int j = 0; j < 8; ++j) {
            p0[j] = (short)tile[kc0 + j][drow];
            p1[j] = (short)tile[kc0 + 8 + j][drow];
        }
        *(short8*)(dst)     = p0;
        *(short8*)(dst + 8) = p1;
    }
}

// ---------------------------------------------------------------------------
// Pre-pass 2: bitpack the mask. int32 0/1 [B][1][S][S] (32 MB) -> 1 bit/elem
// (1 MB, permanently L2-resident). One block per row; wave w, pass p covers
// cols [w*256 + p*64, +64): lane reads one int, __ballot packs 64 bits.
// Bit i of ulong = col (base+i)  (ballot bit == lane index).
// ---------------------------------------------------------------------------
__global__ __launch_bounds__(256)
void maskpack(const int* __restrict__ Msk, unsigned long long* __restrict__ Mb)
{
    const int row  = blockIdx.x;              // 0 .. B*S-1
    const int wave = threadIdx.x >> 6;
    const int lane = threadIdx.x & 63;
    const int* src = Msk + (size_t)row * Sm;
    #pragma unroll
    for (int p = 0; p < 4; ++p) {
        const int col = wave * 256 + p * 64 + lane;
        unsigned long long m = __ballot(src[col] != 0);
        if (lane == 0) Mb[(size_t)row * 16 + wave * 4 + p] = m;
    }
}

// ---------------------------------------------------------------------------
// Main fused kernel (256 threads, 4 waves). R8 post-mortem: TLP-insensitive;
// dur == hbm_bytes / 2.4 TB/s across R6/R7/R8 => effective-BW-bound. This
// round shrinks bytes: bitmask (32 MB + thrash -> 1 MB, L2-resident) and
// Gmx global exchange -> 256 B LDS buffer.
// Strip: 16 x 1024 bf16 XOR-swizzled (col ^ ((row&7)<<3)); row max fused into
// phase A registers, exchanged via LDS smax[4][16].
// ---------------------------------------------------------------------------
__global__ __launch_bounds__(256, 4)
void attn_fused(const float* __restrict__ Q, const unsigned short* __restrict__ Kbf,
                const unsigned short* __restrict__ VT,
                const unsigned long long* __restrict__ Mb,
                float* __restrict__ Out, float* __restrict__ Attn)
{
    __shared__ __align__(16) unsigned short strip[16 * 1024];   // 32 KB
    __shared__ float smax[4][16];                               // [wave][row]

    const int tid  = threadIdx.x;
    const int wave = tid >> 6;
    const int lane = tid & 63;
    const int quad = lane >> 4;
    const int ln   = lane & 15;

    const int bid = (blockIdx.x & 7) * (NBLK >> 3) + (blockIdx.x >> 3);  // XCD swizzle
    const int bh = bid >> 6;
    const int qt = bid & 63;
    const int q0 = qt << 4;
    const int b  = bh >> 4;           // H = 16

    const float* Qb = Q + (size_t)bh * (Sm * Dm);
    const unsigned short* Kb = Kbf + (size_t)bh * (Sm * Dm);
    const unsigned short* Vb = VT + (size_t)bh * (Dm * Sm);

    // ---- Q fragments, 1/sqrt(64)=0.125 folded in (exact: power of 2) ----
    short8 aq0, aq1;
    {
        const float* qrow = Qb + (q0 + ln) * Dm + quad * 8;
        floatx4 a = *(const floatx4*)(qrow);
        floatx4 c = *(const floatx4*)(qrow + 4);
        floatx4 d = *(const floatx4*)(qrow + 32);
        floatx4 e = *(const floatx4*)(qrow + 36);
        #pragma unroll
        for (int i = 0; i < 4; ++i) {
            aq0[i]     = (short)f2bf(a[i] * 0.125f);
            aq0[i + 4] = (short)f2bf(c[i] * 0.125f);
            aq1[i]     = (short)f2bf(d[i] * 0.125f);
            aq1[i + 4] = (short)f2bf(e[i] * 0.125f);
        }
    }

    // ---- Phase A: scores -> swizzled strip; fused per-row max in registers.
    float rm[4] = {-1e30f, -1e30f, -1e30f, -1e30f};
    for (int kt = wave * 16; kt < wave * 16 + 16; ++kt) {
        const unsigned short* krow = Kb + (kt * 16 + ln) * Dm + quad * 8;
        short8 b0 = *(const short8*)(krow);
        short8 b1 = *(const short8*)(krow + 32);
        floatx4 c = {0.f, 0.f, 0.f, 0.f};
        c = __builtin_amdgcn_mfma_f32_16x16x32_bf16(aq0, b0, c, 0, 0, 0);
        c = __builtin_amdgcn_mfma_f32_16x16x32_bf16(aq1, b1, c, 0, 0, 0);
        const int colb = kt * 16 + ln;
        #pragma unroll
        for (int r = 0; r < 4; ++r) {
            const int row = quad * 4 + r;
            rm[r] = fmaxf(rm[r], c[r]);
            strip[row * 1024 + (colb ^ ((row & 7) << 3))] = f2bf(c[r]);
        }
    }
    #pragma unroll
    for (int off = 8; off >= 1; off >>= 1)
        #pragma unroll
        for (int r = 0; r < 4; ++r)
            rm[r] = fmaxf(rm[r], __shfl_xor(rm[r], off, 16));
    if (ln == 0) {
        #pragma unroll
        for (int r = 0; r < 4; ++r) smax[wave][quad * 4 + r] = rm[r];
    }
    __syncthreads();

    // ---- Softmax (2 passes): 16 threads per row ----
    {
        const int row = tid >> 4, l = tid & 15;
        const int sw  = (row & 7) << 3;
        unsigned short* srow = strip + row * 1024;

        float mx = fmaxf(fmaxf(smax[0][row], smax[1][row]),
                         fmaxf(smax[2][row], smax[3][row]));
        mx = bf2f(f2bf(mx));   // == max over bf16-rounded scores (RNE monotone)

        float sum = 0.f;
        #pragma unroll
        for (int i = 0; i < 8; ++i) {
            unsigned short* p8 = srow + ((l * 8 + i * 128) ^ sw);
            short8 v = *(const short8*)p8;
            short8 e;
            #pragma unroll
            for (int j = 0; j < 8; ++j) {
                float x = __expf(bf2f((unsigned short)v[j]) - mx);
                sum += x;
                e[j] = (short)f2bf(x);
            }
            *(short8*)p8 = e;
        }
        #pragma unroll
        for (int off = 8; off >= 1; off >>= 1) sum += __shfl_xor(sum, off, 16);
        const float rn = 1.f / sum;

        // bitmask row: 128 bytes; byte (c0/8) = l + 16*i holds bits for cols c0..c0+7
        const unsigned char* mrow =
            (const unsigned char*)(Mb + ((size_t)b * Sm + (q0 + row)) * 16);
        float* arow = Attn + ((size_t)bh * Sm + (q0 + row)) * Sm;
        #pragma unroll
        for (int i = 0; i < 8; ++i) {
            const int c0 = l * 8 + i * 128;           // logical column
            unsigned short* p8 = srow + (c0 ^ sw);    // swizzled strip location
            short8 v  = *(const short8*)p8;
            const unsigned mu = mrow[l + 16 * i];     // 8 mask bits
            float p[8];
            #pragma unroll
            for (int j = 0; j < 8; ++j)
                p[j] = ((mu >> j) & 1u) ? bf2f((unsigned short)v[j]) * rn : -100000.f;
            floatx4 o0, o1;
            short8 pf;
            #pragma unroll
            for (int j = 0; j < 4; ++j) { o0[j] = p[j]; o1[j] = p[j + 4]; }
            #pragma unroll
            for (int j = 0; j < 8; ++j) pf[j] = (short)f2bf(p[j]);
            *(short8*)p8 = pf;                        // strip now holds P' (bf16)
            *(floatx4*)(arow + c0)     = o0;
            *(floatx4*)(arow + c0 + 4) = o1;
        }
    }
    __syncthreads();

    // ---- Phase B: O = P' @ V. Wave w covers keys [256w, 256w+256). ----
    floatx4 acc[4] = {{0,0,0,0},{0,0,0,0},{0,0,0,0},{0,0,0,0}};
    for (int kb = wave * 256; kb < wave * 256 + 256; kb += 32) {
        short8 af = *(const short8*)(strip + ln * 1024 + ((kb + quad * 8) ^ ((ln & 7) << 3)));
        const unsigned short* vbase = Vb + kb + quad * 8;
        #pragma unroll
        for (int n0 = 0; n0 < 4; ++n0) {
            short8 bf = *(const short8*)(vbase + (size_t)(n0 * 16 + ln) * Sm);
            acc[n0] = __builtin_amdgcn_mfma_f32_16x16x32_bf16(af, bf, acc[n0], 0, 0, 0);
        }
    }
    __syncthreads();

    // ---- Cross-wave partial reduce for O (strip reused as [4][16][64] fp32) ----
    float* part = (float*)strip;                 // 16 KB
    #pragma unroll
    for (int n0 = 0; n0 < 4; ++n0)
        #pragma unroll
        for (int r = 0; r < 4; ++r)
            part[wave * 1024 + (quad * 4 + r) * 64 + n0 * 16 + ln] = acc[n0][r];
    __syncthreads();
    {
        const int o4 = tid * 4;
        floatx4 s = *(const floatx4*)(part + o4);
        s += *(const floatx4*)(part + 1024 + o4);
        s += *(const floatx4*)(part + 2048 + o4);
        s += *(const floatx4*)(part + 3072 + o4);
        const int row = o4 >> 6, dc = o4 & 63;
        *(floatx4*)(Out + (size_t)bh * (Sm * Dm) + (size_t)(q0 + row) * Dm + dc) = s;
    }
}

// ---------------------------------------------------------------------------
// Legacy fallback (fp32 K/V direct, round-1-verified) -- only if ws too small.
// ---------------------------------------------------------------------------
__global__ __launch_bounds__(256, 4)
void attn_fused_f32(const float* __restrict__ Q, const float* __restrict__ K,
                    const float* __restrict__ V, const int* __restrict__ Msk,
                    float* __restrict__ Out, float* __restrict__ Attn)
{
    constexpr int STRIDE = 1040;
    __shared__ __align__(16) unsigned short strip[16 * STRIDE];

    const int tid  = threadIdx.x;
    const int wave = tid >> 6;
    const int lane = tid & 63;
    const int quad = lane >> 4;
    const int ln   = lane & 15;

    const int bid = (blockIdx.x & 7) * (NBLK >> 3) + (blockIdx.x >> 3);
    const int bh = bid >> 6;
    const int qt = bid & 63;
    const int q0 = qt << 4;
    const int b  = bh >> 4;

    const float* Qb = Q + (size_t)bh * (Sm * Dm);
    const float* Kb = K + (size_t)bh * (Sm * Dm);
    const float* Vb = V + (size_t)bh * (Sm * Dm);

    short8 aq0, aq1;
    {
        const float* qrow = Qb + (q0 + ln) * Dm + quad * 8;
        floatx4 a = *(const floatx4*)(qrow);
        floatx4 c = *(const floatx4*)(qrow + 4);
        floatx4 d = *(const floatx4*)(qrow + 32);
        floatx4 e = *(const floatx4*)(qrow + 36);
        #pragma unroll
        for (int i = 0; i < 4; ++i) {
            aq0[i]     = (short)f2bf(a[i] * 0.125f);
            aq0[i + 4] = (short)f2bf(c[i] * 0.125f);
            aq1[i]     = (short)f2bf(d[i] * 0.125f);
            aq1[i + 4] = (short)f2bf(e[i] * 0.125f);
        }
    }

    for (int kt = wave * 16; kt < wave * 16 + 16; ++kt) {
        const float* krow = Kb + (kt * 16 + ln) * Dm + quad * 8;
        floatx4 k0 = *(const floatx4*)(krow);
        floatx4 k1 = *(const floatx4*)(krow + 4);
        floatx4 k2 = *(const floatx4*)(krow + 32);
        floatx4 k3 = *(const floatx4*)(krow + 36);
        short8 b0, b1;
        #pragma unroll
        for (int i = 0; i < 4; ++i) {
            b0[i]     = (short)f2bf(k0[i]);
            b0[i + 4] = (short)f2bf(k1[i]);
            b1[i]     = (short)f2bf(k2[i]);
            b1[i + 4] = (short)f2bf(k3[i]);
        }
        floatx4 c = {0.f, 0.f, 0.f, 0.f};
        c = __builtin_amdgcn_mfma_f32_16x16x32_bf16(aq0, b0, c, 0, 0, 0);
        c = __builtin_amdgcn_mfma_f32_16x16x32_bf16(aq1, b1, c, 0, 0, 0);
        const int colb = kt * 16 + ln;
        #pragma unroll
        for (int r = 0; r < 4; ++r)
            strip[(quad * 4 + r) * STRIDE + colb] = f2bf(c[r]);
    }
    __syncthreads();

    {
        const int row = tid >> 4, l = tid & 15;
        unsigned short* srow = strip + row * STRIDE;

        float mx = -1e30f;
        #pragma unroll
        for (int i = 0; i < 8; ++i) {
            short8 v = *(const short8*)(srow + l * 8 + i * 128);
            #pragma unroll
            for (int j = 0; j < 8; ++j) mx = fmaxf(mx, bf2f((unsigned short)v[j]));
        }
        #pragma unroll
        for (int off = 8; off >= 1; off >>= 1) mx = fmaxf(mx, __shfl_xor(mx, off, 16));

        float sum = 0.f;
        #pragma unroll
        for (int i = 0; i < 8; ++i) {
            short8 v = *(const short8*)(srow + l * 8 + i * 128);
            short8 e;
            #pragma unroll
            for (int j = 0; j < 8; ++j) {
                float x = __expf(bf2f((unsigned short)v[j]) - mx);
                sum += x;
                e[j] = (short)f2bf(x);
            }
            *(short8*)(srow + l * 8 + i * 128) = e;
        }
        #pragma unroll
        for (int off = 8; off >= 1; off >>= 1) sum += __shfl_xor(sum, off, 16);
        const float rn = 1.f / sum;

        const int* mrow  = Msk + (size_t)b * (Sm * Sm) + (size_t)(q0 + row) * Sm;
        float*     arow  = Attn + ((size_t)bh * Sm + (q0 + row)) * Sm;
        #pragma unroll
        for (int i = 0; i < 8; ++i) {
            const int c0 = l * 8 + i * 128;
            short8 v  = *(const short8*)(srow + c0);
            intx4  m0 = *(const intx4*)(mrow + c0);
            intx4  m1 = *(const intx4*)(mrow + c0 + 4);
            float p[8];
            #pragma unroll
            for (int j = 0; j < 4; ++j) {
                p[j]     = (m0[j] != 0) ? bf2f((unsigned short)v[j])     * rn : -100000.f;
                p[j + 4] = (m1[j] != 0) ? bf2f((unsigned short)v[j + 4]) * rn : -100000.f;
            }
            floatx4 o0, o1;
            short8 pf;
            #pragma unroll
            for (int j = 0; j < 4; ++j) { o0[j] = p[j]; o1[j] = p[j + 4]; }
            #pragma unroll
            for (int j = 0; j < 8; ++j) pf[j] = (short)f2bf(p[j]);
            *(short8*)(srow + c0) = pf;
            *(floatx4*)(arow + c0)     = o0;
            *(floatx4*)(arow + c0 + 4) = o1;
        }
    }
    __syncthreads();

    floatx4 acc[4] = {{0,0,0,0},{0,0,0,0},{0,0,0,0},{0,0,0,0}};
    for (int kb = wave * 256; kb < wave * 256 + 256; kb += 32) {
        short8 af = *(const short8*)(strip + ln * STRIDE + kb + quad * 8);
        const float* vbase = Vb + (kb + quad * 8) * Dm + ln;
        #pragma unroll
        for (int n0 = 0; n0 < 4; ++n0) {
            short8 bf;
            #pragma unroll
            for (int j = 0; j < 8; ++j)
                bf[j] = (short)f2bf(vbase[j * Dm + n0 * 16]);
            acc[n0] = __builtin_amdgcn_mfma_f32_16x16x32_bf16(af, bf, acc[n0], 0, 0, 0);
        }
    }
    __syncthreads();

    float* part = (float*)strip;
    #pragma unroll
    for (int n0 = 0; n0 < 4; ++n0)
        #pragma unroll
        for (int r = 0; r < 4; ++r)
            part[wave * 1024 + (quad * 4 + r) * 64 + n0 * 16 + ln] = acc[n0][r];
    __syncthreads();
    {
        const int o4 = tid * 4;
        floatx4 s = *(const floatx4*)(part + o4);
        s += *(const floatx4*)(part + 1024 + o4);
        s += *(const floatx4*)(part + 2048 + o4);
        s += *(const floatx4*)(part + 3072 + o4);
        const int row = o4 >> 6, dc = o4 & 63;
        *(floatx4*)(Out + (size_t)bh * (Sm * Dm) + (size_t)(q0 + row) * Dm + dc) = s;
    }
}

extern "C" void kernel_launch(void* const* d_in, const int* in_sizes, int n_in,
                              void* d_out, int out_size, void* d_ws, size_t ws_size,
                              hipStream_t stream)
{
    const float* Q   = (const float*)d_in[0];
    const float* K   = (const float*)d_in[1];
    const float* V   = (const float*)d_in[2];
    const int*   Msk = (const int*)d_in[3];
    float* Out  = (float*)d_out;
    float* Attn = Out + (size_t)Bm * Hm * Sm * Dm;   // out first, then attn (return order)

    const size_t nElem = (size_t)BH * Sm * Dm;                  // 8.39M
    const size_t bfBytes = nElem * 2 * sizeof(unsigned short);  // Kbf + VT = 32 MB
    const size_t mbBytes = (size_t)Bm * Sm * 16 * sizeof(unsigned long long); // 1 MB
    const size_t need = bfBytes + mbBytes;

    if (d_ws != nullptr && ws_size >= need) {
        unsigned short* Kbf = (unsigned short*)d_ws;
        unsigned short* VT  = Kbf + nElem;
        unsigned long long* Mb = (unsigned long long*)(VT + nElem);
        preconv<<<dim3(BH * 16), dim3(256), 0, stream>>>(K, V, Kbf, VT);
        maskpack<<<dim3(Bm * Sm), dim3(256), 0, stream>>>(Msk, Mb);
        attn_fused<<<dim3(NBLK), dim3(256), 0, stream>>>(Q, Kbf, VT, Mb, Out, Attn);
    } else {
        attn_fused_f32<<<dim3(NBLK), dim3(256), 0, stream>>>(Q, K, V, Msk, Out, Attn);
    }
}